// Round 1
// baseline (653.623 us; speedup 1.0000x reference)
//
#include <hip/hip_runtime.h>
#include <hip/hip_bf16.h>

#define B_ 32
#define S_ 1024
#define D_ 512
#define H_ 8
#define DH_ 64
#define QBLK 64
#define KVB 64
#define NWAVE 4
#define NEGF (-1e30f)

using f32x4 = __attribute__((ext_vector_type(4))) float;
using bf16x8 = __attribute__((ext_vector_type(8))) short;

__device__ __forceinline__ unsigned short f2bf(float f) {
  union { float f; unsigned int u; } v;
  v.f = f;
  unsigned int r = v.u + 0x7fffu + ((v.u >> 16) & 1u);  // RNE, finite inputs
  return (unsigned short)(r >> 16);
}

__device__ __forceinline__ bf16x8 pack8(const float* __restrict__ p) {
  float4 a = *reinterpret_cast<const float4*>(p);
  float4 b = *reinterpret_cast<const float4*>(p + 4);
  bf16x8 r;
  r[0] = (short)f2bf(a.x); r[1] = (short)f2bf(a.y);
  r[2] = (short)f2bf(a.z); r[3] = (short)f2bf(a.w);
  r[4] = (short)f2bf(b.x); r[5] = (short)f2bf(b.y);
  r[6] = (short)f2bf(b.z); r[7] = (short)f2bf(b.w);
  return r;
}

__device__ __forceinline__ f32x4 mfma16(bf16x8 a, bf16x8 b, f32x4 c) {
  return __builtin_amdgcn_mfma_f32_16x16x32_bf16(a, b, c, 0, 0, 0);
}

// ws[0:B*D)        = sum over s of v1[b][s][d]
// ws[B*D : 2*B*D)  = sum over s of v2[b][s][d]
__global__ void colsum_kernel(const float* __restrict__ v1,
                              const float* __restrict__ v2,
                              float* __restrict__ ws) {
  const int b = blockIdx.x >> 4;
  const int chunk = blockIdx.x & 15;
  const int tid = threadIdx.x;
  const int dl = tid & 31;
  const int sg = tid >> 5;  // 0..7
  const int d = chunk * 32 + dl;
  float s1 = 0.f, s2 = 0.f;
  for (int s = sg; s < S_; s += 8) {
    size_t idx = ((size_t)b * S_ + s) * D_ + d;
    s1 += v1[idx];
    s2 += v2[idx];
  }
  __shared__ float r1[256], r2[256];
  r1[tid] = s1; r2[tid] = s2;
  __syncthreads();
  if (sg == 0) {
#pragma unroll
    for (int g = 1; g < 8; ++g) { s1 += r1[g * 32 + dl]; s2 += r2[g * 32 + dl]; }
    ws[b * D_ + d] = s1;
    ws[B_ * D_ + b * D_ + d] = s2;
  }
}

__global__ __launch_bounds__(256) void attn_kernel(
    const float* __restrict__ qg, const float* __restrict__ kg,
    const float* __restrict__ v1g, const float* __restrict__ v2g,
    const int* __restrict__ cmask, const float* __restrict__ colsum,
    float* __restrict__ out) {
  const int qt = blockIdx.x * QBLK;
  const int h = blockIdx.y;
  const int b = blockIdx.z;
  const int tid = threadIdx.x;
  const int wid = tid >> 6;
  const int lane = tid & 63;
  const int l15 = lane & 15;
  const int lg = lane >> 4;  // 0..3

  // K: [kv][dh] swizzled; V1/V2: transposed [dh][kv] swizzled; P: per-wave [q][kv] swizzled
  __shared__ alignas(16) unsigned short sK[KVB * 64];
  __shared__ alignas(16) unsigned short sV1[KVB * 64];
  __shared__ alignas(16) unsigned short sV2[KVB * 64];
  __shared__ alignas(16) unsigned short sP[NWAVE][16 * 64];
  __shared__ int sCnt[KVB];

  // Q fragments (A operand): row = l15 within wave strip, k = jk*32 + lg*8 + i
  bf16x8 qf[2];
  {
    const int qrow = qt + wid * 16 + l15;
    const float* qp = qg + ((size_t)b * S_ + qrow) * D_ + h * DH_;
#pragma unroll
    for (int jk = 0; jk < 2; ++jk) qf[jk] = pack8(qp + jk * 32 + lg * 8);
  }

  f32x4 o1[4], o2[4];
  float m_[4], l_[4];
#pragma unroll
  for (int i = 0; i < 4; ++i) {
    o1[i] = f32x4{0.f, 0.f, 0.f, 0.f};
    o2[i] = f32x4{0.f, 0.f, 0.f, 0.f};
    m_[i] = NEGF;
    l_[i] = 0.f;
  }

  const int ntile = blockIdx.x + 1;  // strictly-causal: tiles 0..qt/64
  for (int ti = 0; ti < ntile; ++ti) {
    const int kv0 = ti * KVB;
    __syncthreads();
    // ---- stage tiles to LDS (fp32 -> bf16)
    {
      const int kvr = tid >> 2;           // 0..63
      const int d0 = (tid & 3) * 16;      // 0,16,32,48
      const size_t roff = ((size_t)b * S_ + kv0 + kvr) * D_ + h * DH_ + d0;
      const int sw = (kvr & 7) << 3;
      bf16x8 ka = pack8(kg + roff);
      bf16x8 kb = pack8(kg + roff + 8);
      *reinterpret_cast<bf16x8*>(&sK[kvr * 64 + (d0 ^ sw)]) = ka;
      *reinterpret_cast<bf16x8*>(&sK[kvr * 64 + ((d0 + 8) ^ sw)]) = kb;

      float vb[16];
#pragma unroll
      for (int i = 0; i < 4; ++i)
        *reinterpret_cast<float4*>(&vb[i * 4]) =
            *reinterpret_cast<const float4*>(v1g + roff + i * 4);
#pragma unroll
      for (int e = 0; e < 16; ++e) {
        const int d = d0 + e;
        sV1[d * 64 + (kvr ^ ((d & 7) << 3))] = f2bf(vb[e]);
      }
#pragma unroll
      for (int i = 0; i < 4; ++i)
        *reinterpret_cast<float4*>(&vb[i * 4]) =
            *reinterpret_cast<const float4*>(v2g + roff + i * 4);
#pragma unroll
      for (int e = 0; e < 16; ++e) {
        const int d = d0 + e;
        sV2[d * 64 + (kvr ^ ((d & 7) << 3))] = f2bf(vb[e]);
      }
      if (tid < KVB) sCnt[tid] = cmask[b * S_ + kv0 + tid];
    }
    __syncthreads();

    // ---- S = Q·K^T : per wave 16 q × 64 keys
    f32x4 sa[4];
#pragma unroll
    for (int nb = 0; nb < 4; ++nb) {
      sa[nb] = f32x4{0.f, 0.f, 0.f, 0.f};
#pragma unroll
      for (int jk = 0; jk < 2; ++jk) {
        const int key = nb * 16 + l15;
        const int idx = key * 64 + ((jk * 32 + lg * 8) ^ ((key & 7) << 3));
        bf16x8 kf = *reinterpret_cast<const bf16x8*>(&sK[idx]);
        sa[nb] = mfma16(qf[jk], kf, sa[nb]);
      }
    }

    // ---- mask + online softmax; C/D layout: col=l15(key), row=lg*4+r (m89)
#pragma unroll
    for (int r = 0; r < 4; ++r) {
      const int qrow = qt + wid * 16 + lg * 4 + r;
      const int prow = lg * 4 + r;
      float sv[4];
      float mx = NEGF;
#pragma unroll
      for (int nb = 0; nb < 4; ++nb) {
        const int key = kv0 + nb * 16 + l15;
        float s = sa[nb][r] * 0.125f;
        const bool ok = (key < qrow) && (sCnt[nb * 16 + l15] != 0);
        s = ok ? s : NEGF;  // exact constant: uniform-softmax semantics preserved
        sv[nb] = s;
        mx = fmaxf(mx, s);
      }
#pragma unroll
      for (int off = 1; off < 16; off <<= 1) mx = fmaxf(mx, __shfl_xor(mx, off));
      const float mnew = fmaxf(m_[r], mx);
      const float fac = __expf(m_[r] - mnew);  // 1 while degenerate, 0 on first real key
      float rs = 0.f;
      const int swp = (prow & 7) << 3;
#pragma unroll
      for (int nb = 0; nb < 4; ++nb) {
        const float p = __expf(sv[nb] - mnew);
        rs += p;
        sP[wid][prow * 64 + ((nb * 16 + l15) ^ swp)] = f2bf(p);
      }
#pragma unroll
      for (int off = 1; off < 16; off <<= 1) rs += __shfl_xor(rs, off);
      l_[r] = l_[r] * fac + rs;
      m_[r] = mnew;
#pragma unroll
      for (int nd = 0; nd < 4; ++nd) { o1[nd][r] *= fac; o2[nd][r] *= fac; }
    }

    // ---- PV: O += P(16x64)·V(64x64), per wave (same-wave LDS RAW, no barrier)
    bf16x8 pa[2];
#pragma unroll
    for (int jk = 0; jk < 2; ++jk) {
      const int idx = l15 * 64 + ((jk * 32 + lg * 8) ^ ((l15 & 7) << 3));
      pa[jk] = *reinterpret_cast<const bf16x8*>(&sP[wid][idx]);
    }
#pragma unroll
    for (int nd = 0; nd < 4; ++nd) {
      const int drow = nd * 16 + l15;
      const int swd = (drow & 7) << 3;
#pragma unroll
      for (int jk = 0; jk < 2; ++jk) {
        const int vidx = drow * 64 + ((jk * 32 + lg * 8) ^ swd);
        bf16x8 v1f = *reinterpret_cast<const bf16x8*>(&sV1[vidx]);
        bf16x8 v2f = *reinterpret_cast<const bf16x8*>(&sV2[vidx]);
        o1[nd] = mfma16(pa[jk], v1f, o1[nd]);
        o2[nd] = mfma16(pa[jk], v2f, o2[nd]);
      }
    }
  }

  // ---- epilogue: normalize; degenerate rows = mean over ALL S keys
  float* outB = out + (size_t)B_ * S_ * D_;
  const size_t obase = (size_t)b * S_ * D_ + h * DH_;
#pragma unroll
  for (int r = 0; r < 4; ++r) {
    const int qrow = qt + wid * 16 + lg * 4 + r;
    const bool deg = (m_[r] <= -9.9e29f);
    const float invl = deg ? (1.0f / (float)S_) : (1.0f / l_[r]);
#pragma unroll
    for (int nd = 0; nd < 4; ++nd) {
      const int d = nd * 16 + l15;
      const float a1 = deg ? colsum[b * D_ + h * DH_ + d] : o1[nd][r];
      const float a2 = deg ? colsum[B_ * D_ + b * D_ + h * DH_ + d] : o2[nd][r];
      out[obase + (size_t)qrow * D_ + d] = a1 * invl;
      outB[obase + (size_t)qrow * D_ + d] = a2 * invl;
    }
  }
}

extern "C" void kernel_launch(void* const* d_in, const int* in_sizes, int n_in,
                              void* d_out, int out_size, void* d_ws, size_t ws_size,
                              hipStream_t stream) {
  const float* q = (const float*)d_in[0];
  const float* k = (const float*)d_in[1];
  const float* v1 = (const float*)d_in[2];
  const float* v2 = (const float*)d_in[3];
  const int* cm = (const int*)d_in[4];
  float* out = (float*)d_out;
  float* ws = (float*)d_ws;  // needs 2*B*D*4 = 128 KiB

  colsum_kernel<<<dim3(B_ * 16), dim3(256), 0, stream>>>(v1, v2, ws);
  attn_kernel<<<dim3(S_ / QBLK, H_, B_), dim3(256), 0, stream>>>(q, k, v1, v2, cm, ws, out);
}